// Round 2
// baseline (570.927 us; speedup 1.0000x reference)
//
#include <hip/hip_runtime.h>
#include <stdint.h>
#include <stdio.h>

#define B_   2
#define T_   1024
#define C_   1024
#define H_   4096
#define ER_  8
#define ES_  2
#define NTOK (B_*T_)   // 2048

typedef __attribute__((ext_vector_type(4))) float  f32x4;
typedef __attribute__((ext_vector_type(8))) __bf16 bf16x8;

__device__ __forceinline__ unsigned short f2bf(float f) {
  unsigned u = __builtin_bit_cast(unsigned, f);
  u += 0x7FFFu + ((u >> 16) & 1u);          // RNE
  return (unsigned short)(u >> 16);
}

__device__ __forceinline__ void async_ld16(void* lds, const void* g) {
  __builtin_amdgcn_global_load_lds(
      (const __attribute__((address_space(1))) char*)(uintptr_t)g,
      (__attribute__((address_space(3))) char*)(uintptr_t)lds, 16, 0, 0);
}

__device__ __forceinline__ f32x4 mfma16(bf16x8 a, bf16x8 b, f32x4 c) {
  return __builtin_amdgcn_mfma_f32_16x16x32_bf16(a, b, c, 0, 0, 0);
}

// -------------------------------------------- per-token norm scales + routing
__global__ void k_prep(const float* __restrict__ u, const float* __restrict__ gs,
                       const float* __restrict__ gr, const float* __restrict__ cent,
                       __bf16* __restrict__ xns, __bf16* __restrict__ xnr,
                       int* __restrict__ tki, float* __restrict__ tkg)
{
  const int t = blockIdx.x, tid = threadIdx.x;
  float4 v = reinterpret_cast<const float4*>(u + (size_t)t * C_)[tid];
  float ss = v.x*v.x + v.y*v.y + v.z*v.z + v.w*v.w;
  const int c0 = tid * 4;
  float sc[ER_];
  #pragma unroll
  for (int e = 0; e < ER_; ++e) {
    sc[e] = v.x * cent[(c0+0)*ER_ + e] + v.y * cent[(c0+1)*ER_ + e]
          + v.z * cent[(c0+2)*ER_ + e] + v.w * cent[(c0+3)*ER_ + e];
  }
  #pragma unroll
  for (int o = 32; o > 0; o >>= 1) {
    ss += __shfl_down(ss, o);
    #pragma unroll
    for (int e = 0; e < ER_; ++e) sc[e] += __shfl_down(sc[e], o);
  }
  __shared__ float red[4][ER_ + 1];
  __shared__ float sbc;
  const int w = tid >> 6;
  if ((tid & 63) == 0) {
    red[w][0] = ss;
    #pragma unroll
    for (int e = 0; e < ER_; ++e) red[w][1 + e] = sc[e];
  }
  __syncthreads();
  if (tid == 0) {
    float S = red[0][0] + red[1][0] + red[2][0] + red[3][0];
    sbc = rsqrtf(S * (1.0f / C_) + 1.1920929e-07f);
    float p[ER_]; float psum = 0.f;
    #pragma unroll
    for (int e = 0; e < ER_; ++e) {
      float d = red[0][1+e] + red[1][1+e] + red[2][1+e] + red[3][1+e];
      p[e] = 1.f / (1.f + expf(-d));
      psum += p[e];
    }
    int i0 = 0;
    for (int e = 1; e < ER_; ++e) if (p[e] > p[i0]) i0 = e;
    int i1 = -1;
    for (int e = 0; e < ER_; ++e) { if (e == i0) continue; if (i1 < 0 || p[e] > p[i1]) i1 = e; }
    tki[t*2+0] = i0;  tki[t*2+1] = i1;
    tkg[t*2+0] = p[i0] / psum;  tkg[t*2+1] = p[i1] / psum;
  }
  __syncthreads();
  const float s = sbc;
  ushort4 os, orr;
  os.x  = f2bf(v.x * s * gs[c0+0]); os.y  = f2bf(v.y * s * gs[c0+1]);
  os.z  = f2bf(v.z * s * gs[c0+2]); os.w  = f2bf(v.w * s * gs[c0+3]);
  orr.x = f2bf(v.x * s * gr[c0+0]); orr.y = f2bf(v.y * s * gr[c0+1]);
  orr.z = f2bf(v.z * s * gr[c0+2]); orr.w = f2bf(v.w * s * gr[c0+3]);
  reinterpret_cast<ushort4*>(xns)[(size_t)t * (C_/4) + tid] = os;
  reinterpret_cast<ushort4*>(xnr)[(size_t)t * (C_/4) + tid] = orr;
}

// -------------------------------------------------- expert token-list builder
__global__ void k_build(const int* __restrict__ tki, const float* __restrict__ tkg,
                        int* __restrict__ listTok, float* __restrict__ listGate,
                        int* __restrict__ offs, int* __restrict__ cnts)
{
  __shared__ int cnt[ER_], cur[ER_], off[ER_];
  const int tid = threadIdx.x;
  if (tid < ER_) cnt[tid] = 0;
  __syncthreads();
  for (int i = tid; i < NTOK*2; i += 256) atomicAdd(&cnt[tki[i]], 1);
  __syncthreads();
  if (tid == 0) {
    int a = 0;
    for (int e = 0; e < ER_; ++e) { off[e] = a; cur[e] = a; a += cnt[e]; }
  }
  __syncthreads();
  for (int i = tid; i < NTOK*2; i += 256) {
    int e = tki[i];
    int p = atomicAdd(&cur[e], 1);
    listTok[p]  = i >> 1;
    listGate[p] = tkg[i];
  }
  if (tid < ER_) { offs[tid] = off[tid]; cnts[tid] = cnt[tid]; }
}

// --------------------------------- weight transpose + fp32->bf16 ([K][N]->[N][K])
__global__ void k_convT(const float* __restrict__ src, __bf16* __restrict__ dst,
                        int K, int N)
{
  const int e = blockIdx.z;
  src += (size_t)e * K * N;
  unsigned short* d = reinterpret_cast<unsigned short*>(dst) + (size_t)e * K * N;
  const int n0 = blockIdx.x * 64, k0 = blockIdx.y * 64;
  __shared__ float tb[64][65];
  const int tid = threadIdx.x;
  const int r = tid >> 4, c = (tid & 15) * 4;
  #pragma unroll
  for (int rr = r; rr < 64; rr += 16) {
    float4 v = *reinterpret_cast<const float4*>(&src[(size_t)(k0+rr)*N + n0 + c]);
    tb[rr][c] = v.x; tb[rr][c+1] = v.y; tb[rr][c+2] = v.z; tb[rr][c+3] = v.w;
  }
  __syncthreads();
  #pragma unroll
  for (int rr = r; rr < 64; rr += 16) {
    ushort4 o;
    o.x = f2bf(tb[c+0][rr]); o.y = f2bf(tb[c+1][rr]);
    o.z = f2bf(tb[c+2][rr]); o.w = f2bf(tb[c+3][rr]);
    *reinterpret_cast<ushort4*>(&d[(size_t)(n0+rr)*K + k0 + c]) = o;
  }
}

// ------------------------------------------------------------- tiled bf16 GEMM
// BM=128 x BN tile, BK=32, 4 waves (2x2), 16x16x32 MFMA.
// Double-buffered LDS, prefetch-next-then-compute (T3 minimal 2-phase).
// LDS XOR involution swizzle (chunk ^= (row>>1)&3, 16B chunks) applied to the
// global SOURCE at staging and to the ds_read chunk (rule 21: both sides).
// MODE 0: dense, hid = gelu(A*Wt + b1)                 (shared gemm1, N=2H)
// MODE 1: gathered A, hid = gelu(A*Wt + b1)            (routed gemm1)
// MODE 2: dense, out = u + b2[0]+b2[1] + A*Wt          (shared gemm2, K=2H)
// MODE 3: slot A, out += gate*(A*Wt + b2)  atomically  (routed gemm2)
template<int KDIM, int NDIM, int BN, int MODE>
__global__ __launch_bounds__(256)
void k_gemm(const __bf16* __restrict__ Abase, const __bf16* __restrict__ Wt,
            const float* __restrict__ bias, __bf16* __restrict__ hid,
            float* __restrict__ out, const float* __restrict__ u,
            const int* __restrict__ listTok, const float* __restrict__ listGate,
            const int* __restrict__ offs, const int* __restrict__ cnts)
{
  constexpr int NF = BN / 32;               // n-frags per wave
  constexpr bool ROUTED = (MODE == 1 || MODE == 3);
  const int e = blockIdx.z;
  int M, slotbase;
  if (ROUTED) { M = cnts[e]; slotbase = offs[e]; }
  else        { M = NTOK;    slotbase = 0; }

  // XCD-chunked bijective swizzle; m (blockIdx.x) is fastest so all m-blocks
  // sharing one W n-slice land contiguously on one XCD.
  const int gx = gridDim.x;
  const int lin = blockIdx.y * gx + blockIdx.x;
  const int nblk = gx * gridDim.y;
  const int q = nblk >> 3, rm = nblk & 7;
  const int xcd = lin & 7, idx = lin >> 3;
  const int swz = (xcd < rm ? xcd * (q + 1) : rm * (q + 1) + (xcd - rm) * q) + idx;
  const int m0 = (swz % gx) * 128;
  if (m0 >= M) return;
  const int n0 = (swz / gx) * BN;

  const int tid = threadIdx.x;
  const int w = tid >> 6, l = tid & 63;

  __shared__ __align__(16) __bf16 Al[2][128 * 32];
  __shared__ __align__(16) __bf16 Bl[2][BN * 32];

  // ---- staging addresses (swizzled source chunk) ----
  const int sr = tid >> 2;                                  // 0..63
  const int csrc = ((tid & 3) ^ ((tid >> 3) & 3)) * 8;      // elems
  int r0 = m0 + sr;       if (r0 >= M) r0 = M - 1;
  int r1 = m0 + 64 + sr;  if (r1 >= M) r1 = M - 1;
  size_t arow0, arow1;
  if (MODE == 1)      { arow0 = (size_t)listTok[slotbase + r0]; arow1 = (size_t)listTok[slotbase + r1]; }
  else if (MODE == 3) { arow0 = (size_t)(slotbase + r0);        arow1 = (size_t)(slotbase + r1); }
  else                { arow0 = (size_t)r0;                     arow1 = (size_t)r1; }
  const __bf16* ga0 = Abase + arow0 * KDIM + csrc;
  const __bf16* ga1 = Abase + arow1 * KDIM + csrc;
  const __bf16* gb0 = Wt + ((size_t)e * NDIM + n0 + sr) * KDIM + csrc;
  const __bf16* gb1 = gb0 + (size_t)64 * KDIM;
  const unsigned wofs = w * 1024;

  auto stage = [&](int buf, int k0) {
    char* ab = (char*)Al + buf * 8192 + wofs;
    async_ld16(ab,        ga0 + k0);
    async_ld16(ab + 4096, ga1 + k0);
    char* bb = (char*)Bl + buf * (BN * 64) + wofs;
    async_ld16(bb, gb0 + k0);
    if constexpr (BN == 128) async_ld16(bb + 4096, gb1 + k0);
  };

  // ---- fragment read offsets (swizzled chunk) ----
  const int wr = (w >> 1) * 64;
  const int wc = (w & 1) * (BN / 2);
  const int lrow = l & 15;
  const int kq = ((l >> 4) ^ ((l >> 1) & 3)) * 8;

  f32x4 acc[4][NF];
  #pragma unroll
  for (int m = 0; m < 4; ++m)
    #pragma unroll
    for (int n = 0; n < NF; ++n) acc[m][n] = (f32x4){0.f, 0.f, 0.f, 0.f};

  auto compute = [&](int buf) {
    bf16x8 af[4], bfr[NF];
    #pragma unroll
    for (int m = 0; m < 4; ++m)
      af[m] = *reinterpret_cast<const bf16x8*>(&Al[buf][(wr + m*16 + lrow)*32 + kq]);
    #pragma unroll
    for (int n = 0; n < NF; ++n)
      bfr[n] = *reinterpret_cast<const bf16x8*>(&Bl[buf][(wc + n*16 + lrow)*32 + kq]);
    #pragma unroll
    for (int m = 0; m < 4; ++m)
      #pragma unroll
      for (int n = 0; n < NF; ++n)
        acc[m][n] = mfma16(af[m], bfr[n], acc[m][n]);
  };

  // ---- pipelined K-loop: stage(t+1) || compute(t); one barrier per tile ----
  stage(0, 0);
  __syncthreads();
  int cur = 0;
  for (int k0 = 32; k0 < KDIM; k0 += 32) {
    stage(cur ^ 1, k0);
    compute(cur);
    __syncthreads();
    cur ^= 1;
  }
  compute(cur);

  // ---- epilogue — C/D layout: col = lane&15, row = (lane>>4)*4 + reg ----
  #pragma unroll
  for (int m = 0; m < 4; ++m) {
    const int rbase = m0 + wr + m*16 + (l >> 4) * 4;
    #pragma unroll
    for (int rg = 0; rg < 4; ++rg) {
      const int r = rbase + rg;
      if (r >= M) continue;
      if constexpr (MODE == 0) {
        #pragma unroll
        for (int n = 0; n < NF; ++n) {
          const int col = n0 + wc + n*16 + lrow;
          float v = acc[m][n][rg] + bias[col];
          v = 0.5f * v * (1.0f + erff(v * 0.70710678118654752f));
          reinterpret_cast<unsigned short*>(hid)[(size_t)r * NDIM + col] = f2bf(v);
        }
      } else if constexpr (MODE == 1) {
        #pragma unroll
        for (int n = 0; n < NF; ++n) {
          const int col = n0 + wc + n*16 + lrow;
          float v = acc[m][n][rg] + bias[e * NDIM + col];
          v = 0.5f * v * (1.0f + erff(v * 0.70710678118654752f));
          reinterpret_cast<unsigned short*>(hid)[(size_t)(slotbase + r) * NDIM + col] = f2bf(v);
        }
      } else if constexpr (MODE == 2) {
        #pragma unroll
        for (int n = 0; n < NF; ++n) {
          const int col = n0 + wc + n*16 + lrow;
          float v = acc[m][n][rg] + bias[col] + bias[C_ + col] + u[(size_t)r * C_ + col];
          out[(size_t)r * C_ + col] = v;
        }
      } else {
        const int tok = listTok[slotbase + r];
        const float g = listGate[slotbase + r];
        #pragma unroll
        for (int n = 0; n < NF; ++n) {
          const int col = n0 + wc + n*16 + lrow;
          float v = acc[m][n][rg] + bias[e * C_ + col];
          unsafeAtomicAdd(&out[(size_t)tok * C_ + col], g * v);
        }
      }
    }
  }
}

// -----------------------------------------------------------------------------
extern "C" void kernel_launch(void* const* d_in, const int* in_sizes, int n_in,
                              void* d_out, int out_size, void* d_ws, size_t ws_size,
                              hipStream_t stream)
{
  const float* u    = (const float*)d_in[0];
  const float* gs   = (const float*)d_in[1];
  const float* W1s  = (const float*)d_in[2];
  const float* b1s  = (const float*)d_in[3];
  const float* W2s  = (const float*)d_in[4];
  const float* b2s  = (const float*)d_in[5];
  const float* gr   = (const float*)d_in[6];
  const float* W1r  = (const float*)d_in[7];
  const float* b1r  = (const float*)d_in[8];
  const float* W2r  = (const float*)d_in[9];
  const float* b2r  = (const float*)d_in[10];
  const float* cent = (const float*)d_in[11];
  float* out = (float*)d_out;

  char* ws = (char*)d_ws;
  size_t off = 0;
  auto alloc = [&](size_t bytes) -> char* {
    char* p = ws + off;
    off += (bytes + 255) & ~(size_t)255;
    return p;
  };
  __bf16* wbuf = (__bf16*)alloc((size_t)(ES_ + ER_) * H_ * C_ * 2);  // 84 MB, reused W1t->W2t
  __bf16* xns  = (__bf16*)alloc((size_t)NTOK * C_ * 2);
  __bf16* xnr  = (__bf16*)alloc((size_t)NTOK * C_ * 2);
  __bf16* hids = (__bf16*)alloc((size_t)NTOK * (ES_*H_) * 2);        // [2048][8192] bf16
  __bf16* hidr = (__bf16*)alloc((size_t)NTOK * 2 * H_ * 2);          // [4096 slots][4096]
  int*    tki      = (int*)  alloc(NTOK * 2 * 4);
  float*  tkg      = (float*)alloc(NTOK * 2 * 4);
  int*    listTok  = (int*)  alloc(NTOK * 2 * 4);
  float*  listGate = (float*)alloc(NTOK * 2 * 4);
  int*    offs     = (int*)  alloc(64);
  int*    cnts     = (int*)  alloc(64);
  if (off > ws_size) {
    fprintf(stderr, "ATHENA: WORKSPACE TOO SMALL: need %zu bytes, have %zu\n", off, ws_size);
    return;
  }

  __bf16* wt_s = wbuf;                       // shared experts (stacked)
  __bf16* wt_r = wbuf + (size_t)ES_ * H_ * C_;

  k_prep<<<dim3(NTOK), dim3(256), 0, stream>>>(u, gs, gr, cent, xns, xnr, tki, tkg);
  k_build<<<dim3(1), dim3(256), 0, stream>>>(tki, tkg, listTok, listGate, offs, cnts);

  // W1 [E][C][H] -> bf16 [E*H][C]
  k_convT<<<dim3(H_/64, C_/64, ES_), dim3(256), 0, stream>>>(W1s, wt_s, C_, H_);
  k_convT<<<dim3(H_/64, C_/64, ER_), dim3(256), 0, stream>>>(W1r, wt_r, C_, H_);

  // shared gemm1: dense [2048,1024] x [8192,1024]^T -> hids [2048][8192]
  k_gemm<C_, ES_*H_, 128, 0><<<dim3(16, 64, 1), dim3(256), 0, stream>>>(
      xns, wt_s, b1s, hids, nullptr, nullptr, nullptr, nullptr, nullptr, nullptr);
  // routed gemm1: grouped
  k_gemm<C_, H_, 128, 1><<<dim3(16, 32, ER_), dim3(256), 0, stream>>>(
      xnr, wt_r, b1r, hidr, nullptr, nullptr, listTok, listGate, offs, cnts);

  // W2: shared stacked [2H][C] -> [C][2H]; routed per-expert [H][C] -> [C][H]
  k_convT<<<dim3(C_/64, (ES_*H_)/64, 1), dim3(256), 0, stream>>>(W2s, wt_s, ES_*H_, C_);
  k_convT<<<dim3(C_/64, H_/64, ER_), dim3(256), 0, stream>>>(W2r, wt_r, H_, C_);

  // shared gemm2: out = u + b2s[0]+b2s[1] + hids x wt_s   (non-atomic, covers all)
  k_gemm<ES_*H_, C_, 64, 2><<<dim3(16, 16, 1), dim3(256), 0, stream>>>(
      hids, wt_s, b2s, nullptr, out, u, nullptr, nullptr, nullptr, nullptr);
  // routed gemm2: atomic out += gate*(hidr x wt_r + b2r)
  k_gemm<H_, C_, 64, 3><<<dim3(16, 16, ER_), dim3(256), 0, stream>>>(
      hidr, wt_r, b2r, nullptr, out, nullptr, listTok, listGate, offs, cnts);
}